// Round 3
// baseline (339.886 us; speedup 1.0000x reference)
//
#include <hip/hip_runtime.h>

// Per-batch segment_sum over sorted segment ids.
// B=16, L=4096, H=768, fp32. out[b,j,:] = sum_{p: seg[b,p]==j} x[b,p,:].
// Sorted ids => token j's rows are [lower_bound(seg_b,j), lower_bound(seg_b,j+1)).
#define BB 16
#define LL 4096
#define H4 192   // 768 floats = 192 float4 per row
#define TPW 4    // tokens per wave

// One wave handles TPW consecutive tokens [j0, j0+TPW): it streams input rows
// [lower_bound(j0), lower_bound(j0+TPW)) once, in order, with a 2-deep software
// pipeline (next row's loads in flight while current row is accumulated), and
// flushes the accumulator at (wave-uniform) token boundaries.
__global__ __launch_bounds__(256) void segsum_kernel(
    const float4* __restrict__ x, const int* __restrict__ seg,
    float4* __restrict__ out) {
    int gtid = blockIdx.x * blockDim.x + threadIdx.x;
    int wave = gtid >> 6;            // 0 .. B*L/TPW - 1
    int lane = gtid & 63;
    int b  = wave >> 10;             // / (L/TPW = 1024)
    int j0 = (wave & 1023) << 2;     // first token of this wave

    const int* __restrict__ sb = seg + ((size_t)b << 12);

    // --- two-step 64-ary ballot lower_bound searches, shared step-1 probe ---
    int v1 = sb[lane << 6];
    unsigned long long ms = __ballot(v1 >= j0);
    unsigned long long me = __ballot(v1 >= (j0 + TPW));

    int s, e;
    if (ms & 1ull) {
        s = 0;
    } else {
        int f = ms ? (__ffsll(ms) - 1) : 64;
        int base = ((f - 1) << 6) + 1;
        int p2 = base + lane;
        int v2 = (p2 < LL) ? sb[p2] : 0x7fffffff;   // seg[L] := +inf
        unsigned long long m2 = __ballot(v2 >= j0);
        s = base + __ffsll(m2) - 1;
    }
    if (me & 1ull) {
        e = 0;
    } else {
        int f = me ? (__ffsll(me) - 1) : 64;
        int base = ((f - 1) << 6) + 1;
        int p2 = base + lane;
        int v2 = (p2 < LL) ? sb[p2] : 0x7fffffff;
        unsigned long long m2 = __ballot(v2 >= (j0 + TPW));
        e = base + __ffsll(m2) - 1;
    }

    const float4* xb = x + (size_t)b * LL * H4;
    float4* ob = out + (((size_t)b << 12) + j0) * H4 + lane;

    float4 a0 = make_float4(0.f, 0.f, 0.f, 0.f), a1 = a0, a2 = a0;
    int d = 0;   // current token offset within [0, TPW)

    // --- streaming pass with 2-deep pipeline ---
    float4 b0 = a0, b1 = a0, b2 = a0;
    int sp = 0;
    int p = s;
    if (p < e) {
        const float4* row = xb + (size_t)p * H4 + lane;
        b0 = row[0]; b1 = row[64]; b2 = row[128];
        sp = sb[p];                  // wave-uniform (broadcast, cache-hot)
    }
    while (p < e) {
        int pn = p + 1;
        float4 c0 = a0, c1 = a0, c2 = a0;
        int spn = 0;
        if (pn < e) {                // prefetch next row + its segment id
            const float4* row = xb + (size_t)pn * H4 + lane;
            c0 = row[0]; c1 = row[64]; c2 = row[128];
            spn = sb[pn];
        }
        // flush finished tokens (uniform branch; empty tokens write zeros)
        while (j0 + d < sp) {
            float4* orow = ob + (size_t)d * H4;
            orow[0] = a0; orow[64] = a1; orow[128] = a2;
            a0 = make_float4(0.f, 0.f, 0.f, 0.f); a1 = a0; a2 = a0;
            ++d;
        }
        a0.x += b0.x; a0.y += b0.y; a0.z += b0.z; a0.w += b0.w;
        a1.x += b1.x; a1.y += b1.y; a1.z += b1.z; a1.w += b1.w;
        a2.x += b2.x; a2.y += b2.y; a2.z += b2.z; a2.w += b2.w;
        b0 = c0; b1 = c1; b2 = c2; sp = spn;
        p = pn;
    }
    // flush remaining tokens (incl. all-empty wave: 4 zero rows)
    while (d < TPW) {
        float4* orow = ob + (size_t)d * H4;
        orow[0] = a0; orow[64] = a1; orow[128] = a2;
        a0 = make_float4(0.f, 0.f, 0.f, 0.f); a1 = a0; a2 = a0;
        ++d;
    }
}

extern "C" void kernel_launch(void* const* d_in, const int* in_sizes, int n_in,
                              void* d_out, int out_size, void* d_ws, size_t ws_size,
                              hipStream_t stream) {
    const float* x   = (const float*)d_in[0];   // (B, L, H) fp32
    const int*   seg = (const int*)d_in[1];     // (B, L) int32, sorted per row
    float* out = (float*)d_out;                 // (B, L, H) fp32
    (void)d_ws; (void)ws_size;

    // B*L/TPW = 16384 waves, 4 waves per 256-thread block -> 4096 blocks
    int nblocks = (BB * LL / TPW) / 4;
    segsum_kernel<<<nblocks, 256, 0, stream>>>(
        (const float4*)x, seg, (float4*)out);
}